// Round 3
// baseline (522.202 us; speedup 1.0000x reference)
//
#include <hip/hip_runtime.h>
#include <hip/hip_bf16.h>
#include <stdint.h>

#define NTOK   8192
#define DM     1024
#define DFF    1024
#define NEXP   64
#define TOPK   2
#define NEXPAND (NTOK*TOPK)   // 16384
#define CAP    512            // (2*N)/E

typedef __attribute__((ext_vector_type(4))) float f32x4;
typedef __attribute__((ext_vector_type(8))) short bf16x8;
typedef __attribute__((ext_vector_type(4))) short short4v;

__device__ __forceinline__ short f2bf(float f) {
  __hip_bfloat16 h = __float2bfloat16(f);
  union { __hip_bfloat16 h; short s; } u; u.h = h; return u.s;
}

__device__ __forceinline__ void gload16(const void* g, void* l) {
  __builtin_amdgcn_global_load_lds(
      (const __attribute__((address_space(1))) unsigned int*)g,
      (__attribute__((address_space(3))) unsigned int*)l, 16, 0, 0);
}

// ---------------- routing: exact sequential per-expert cumcount ----------------
__global__ __launch_bounds__(256) void k_route(const int* __restrict__ idx,
                                               int* __restrict__ slot_token,
                                               int* __restrict__ comb_slot) {
  const int ee = blockIdx.x;
  const int tid = threadIdx.x;
  const int lane = tid & 63;
  const int wv = tid >> 6;
  __shared__ int wsum[4];
  int base = 0;
  for (int it = 0; it < NEXPAND / 256; ++it) {
    int i = it * 256 + tid;
    bool m = (idx[i] == ee);
    unsigned long long bal = __ballot(m);
    int pre = __popcll(bal & ((1ull << lane) - 1ull));
    int wtot = __popcll(bal);
    if (lane == 0) wsum[wv] = wtot;
    __syncthreads();
    int wbase = 0, tot = 0;
#pragma unroll
    for (int w = 0; w < 4; ++w) { if (w < wv) wbase += wsum[w]; tot += wsum[w]; }
    if (m) {
      int pos = base + wbase + pre;
      if (pos < CAP) {
        comb_slot[i] = ee * CAP + pos;
        slot_token[ee * CAP + pos] = i >> 1;   // token index (k=2)
      } else {
        comb_slot[i] = -1;                      // dropped over capacity
      }
    }
    base += tot;
    __syncthreads();
  }
  int filled = base < CAP ? base : CAP;
  for (int p = filled + tid; p < CAP; p += 256) slot_token[ee * CAP + p] = -1;
}

// ---------------- dispatch: gather + f32->bf16 ----------------
__global__ __launch_bounds__(256) void k_dispatch(const float* __restrict__ hidden,
                                                  const int* __restrict__ slot_token,
                                                  short* __restrict__ xd) {
  int row = blockIdx.x;
  int tok = slot_token[row];
  int c = threadIdx.x * 4;
  short4v v;
  if (tok >= 0) {
    float4 f = *(const float4*)(hidden + (size_t)tok * DM + c);
    v[0] = f2bf(f.x); v[1] = f2bf(f.y); v[2] = f2bf(f.z); v[3] = f2bf(f.w);
  } else {
    v[0] = 0; v[1] = 0; v[2] = 0; v[3] = 0;
  }
  *(short4v*)(xd + (size_t)row * DM + c) = v;
}

// LDS tiles: [row][64 bf16] rows of 128B; physical chunk = logical chunk ^ (row&7).
// A tiles DMA'd linear -> pre-swizzle the GLOBAL source column (m173 pattern).
// B tiles reg-staged -> XOR on ds_write and ds_read.

// ---------------- GEMM1: act = silu(x@Wg) * (x@Wu) ----------------
// tile 128 x (64 gate + 64 up), BK=64, 4 waves; 2-phase pipeline:
// A dbuf via global_load_lds, B prefetched to regs one step ahead.
__global__ __launch_bounds__(256) void k_gemm1(const short* __restrict__ xd,
                                               const float* __restrict__ gup,
                                               short* __restrict__ act) {
  __shared__ short As[2][128 * 64];
  __shared__ short Bg[64 * 64];
  __shared__ short Bu[64 * 64];
  int bid0 = blockIdx.x;
  int bid = (bid0 & 7) * (NEXP * 64 / 8) + (bid0 >> 3);   // XCD chunked swizzle
  const int e  = bid >> 6;
  const int mt = (bid >> 4) & 3;
  const int nt = bid & 15;
  const int tid = threadIdx.x;
  const int lane = tid & 63;
  const int wid = tid >> 6;
  const int wm = wid >> 1;
  const int wn = wid & 1;

  const short* Abase = xd + (size_t)(e * CAP + mt * 128) * DM;
  const float* Wg = gup + (size_t)e * DM * (2 * DFF) + nt * 64;

  const int arow = lane >> 3;
  const int acol = ((lane & 7) ^ arow) * 8;

  // B gather: col-pair per lane-group; n2 = col pair, kg = k-octet
  const int n2 = tid & 31;
  const int kg = tid >> 5;
  const int r0 = 2 * n2, r1 = 2 * n2 + 1;
  const int w0off = r0 * 64 + ((kg ^ (r0 & 7)) * 8);
  const int w1off = r1 * 64 + ((kg ^ (r1 & 7)) * 8);

  f32x4 accg[4][2], accu[4][2];
#pragma unroll
  for (int m = 0; m < 4; ++m)
#pragma unroll
    for (int n = 0; n < 2; ++n) { accg[m][n] = (f32x4)0.f; accu[m][n] = (f32x4)0.f; }

  float2 gv[8], uv[8];
  // prologue: issue tile 0
#pragma unroll
  for (int q = 0; q < 4; ++q) {
    int c = wid * 4 + q;
    gload16(Abase + (size_t)(c * 8 + arow) * DM + acol, &As[0][c * 512]);
  }
  {
    const float* gq = Wg + (size_t)(kg * 8) * (2 * DFF) + n2 * 2;
#pragma unroll
    for (int j = 0; j < 8; ++j) {
      gv[j] = *(const float2*)(gq + (size_t)j * (2 * DFF));
      uv[j] = *(const float2*)(gq + (size_t)j * (2 * DFF) + DFF);
    }
  }

  for (int t = 0; t < 16; ++t) {
    const int cur = t & 1;
    __builtin_amdgcn_s_barrier();                    // LDS of step t-1 free
    asm volatile("s_waitcnt vmcnt(0)" ::: "memory"); // B(t) regs + A(t) dma landed
    // stage B(t) into LDS
    bf16x8 wg0 = { f2bf(gv[0].x), f2bf(gv[1].x), f2bf(gv[2].x), f2bf(gv[3].x),
                   f2bf(gv[4].x), f2bf(gv[5].x), f2bf(gv[6].x), f2bf(gv[7].x) };
    bf16x8 wg1 = { f2bf(gv[0].y), f2bf(gv[1].y), f2bf(gv[2].y), f2bf(gv[3].y),
                   f2bf(gv[4].y), f2bf(gv[5].y), f2bf(gv[6].y), f2bf(gv[7].y) };
    bf16x8 wu0 = { f2bf(uv[0].x), f2bf(uv[1].x), f2bf(uv[2].x), f2bf(uv[3].x),
                   f2bf(uv[4].x), f2bf(uv[5].x), f2bf(uv[6].x), f2bf(uv[7].x) };
    bf16x8 wu1 = { f2bf(uv[0].y), f2bf(uv[1].y), f2bf(uv[2].y), f2bf(uv[3].y),
                   f2bf(uv[4].y), f2bf(uv[5].y), f2bf(uv[6].y), f2bf(uv[7].y) };
    *(bf16x8*)&Bg[w0off] = wg0;
    *(bf16x8*)&Bg[w1off] = wg1;
    *(bf16x8*)&Bu[w0off] = wu0;
    *(bf16x8*)&Bu[w1off] = wu1;
    // issue tile t+1 (stays in flight across the MFMA phase)
    if (t < 15) {
      const int k0 = (t + 1) * 64;
#pragma unroll
      for (int q = 0; q < 4; ++q) {
        int c = wid * 4 + q;
        gload16(Abase + (size_t)(c * 8 + arow) * DM + k0 + acol, &As[cur ^ 1][c * 512]);
      }
      const float* gq = Wg + (size_t)(k0 + kg * 8) * (2 * DFF) + n2 * 2;
#pragma unroll
      for (int j = 0; j < 8; ++j) {
        gv[j] = *(const float2*)(gq + (size_t)j * (2 * DFF));
        uv[j] = *(const float2*)(gq + (size_t)j * (2 * DFF) + DFF);
      }
    }
    asm volatile("s_waitcnt lgkmcnt(0)" ::: "memory");
    __builtin_amdgcn_s_barrier();
    // MFMA on tile t
#pragma unroll
    for (int kh = 0; kh < 2; ++kh) {
      const int kq = kh * 4 + (lane >> 4);
      const int co = (kq ^ (lane & 7)) * 8;
      bf16x8 a[4], bgf[2], buf_[2];
#pragma unroll
      for (int m = 0; m < 4; ++m)
        a[m] = *(const bf16x8*)&As[cur][(wm * 64 + m * 16 + (lane & 15)) * 64 + co];
#pragma unroll
      for (int n = 0; n < 2; ++n) {
        bgf[n]  = *(const bf16x8*)&Bg[(wn * 32 + n * 16 + (lane & 15)) * 64 + co];
        buf_[n] = *(const bf16x8*)&Bu[(wn * 32 + n * 16 + (lane & 15)) * 64 + co];
      }
#pragma unroll
      for (int m = 0; m < 4; ++m)
#pragma unroll
        for (int n = 0; n < 2; ++n) {
          accg[m][n] = __builtin_amdgcn_mfma_f32_16x16x32_bf16(a[m], bgf[n], accg[m][n], 0, 0, 0);
          accu[m][n] = __builtin_amdgcn_mfma_f32_16x16x32_bf16(a[m], buf_[n], accu[m][n], 0, 0, 0);
        }
    }
  }
  // fused SwiGLU epilogue -> act bf16
  short* obase = act + (size_t)(e * CAP + mt * 128) * DFF + nt * 64;
#pragma unroll
  for (int m = 0; m < 4; ++m)
#pragma unroll
    for (int n = 0; n < 2; ++n)
#pragma unroll
      for (int j = 0; j < 4; ++j) {
        int rl = wm * 64 + m * 16 + (lane >> 4) * 4 + j;
        int cl = wn * 32 + n * 16 + (lane & 15);
        float g = accg[m][n][j];
        float u = accu[m][n][j];
        float s = (g / (1.f + __expf(-g))) * u;
        obase[(size_t)rl * DFF + cl] = f2bf(s);
      }
}

// ---------------- GEMM2: yd = act @ down ----------------
// tile 128 x 128, BK=64, 4 waves; same 2-phase pipeline
__global__ __launch_bounds__(256) void k_gemm2(const short* __restrict__ act,
                                               const float* __restrict__ down,
                                               float* __restrict__ yd) {
  __shared__ short As[2][128 * 64];
  __shared__ short Bt[128 * 64];
  int bid0 = blockIdx.x;
  int bid = (bid0 & 7) * (NEXP * 32 / 8) + (bid0 >> 3);   // XCD chunked swizzle
  const int e  = bid >> 5;
  const int mt = (bid >> 3) & 3;
  const int nt = bid & 7;
  const int tid = threadIdx.x;
  const int lane = tid & 63;
  const int wid = tid >> 6;
  const int wm = wid >> 1;
  const int wn = wid & 1;

  const short* Abase = act + (size_t)(e * CAP + mt * 128) * DFF;
  const float* Wb = down + (size_t)e * DFF * DM + nt * 128;

  const int arow = lane >> 3;
  const int acol = ((lane & 7) ^ arow) * 8;

  // B gather: col-pair per lane (128 cols -> n2=tid&63), k-quarter = wid
  const int n2 = tid & 63;
  const int r0 = 2 * n2, r1 = 2 * n2 + 1;
  const int c0 = wid * 2, c1 = wid * 2 + 1;
  const int w00 = r0 * 64 + ((c0 ^ (r0 & 7)) * 8);
  const int w01 = r0 * 64 + ((c1 ^ (r0 & 7)) * 8);
  const int w10 = r1 * 64 + ((c0 ^ (r1 & 7)) * 8);
  const int w11 = r1 * 64 + ((c1 ^ (r1 & 7)) * 8);

  f32x4 acc[4][4];
#pragma unroll
  for (int m = 0; m < 4; ++m)
#pragma unroll
    for (int n = 0; n < 4; ++n) acc[m][n] = (f32x4)0.f;

  float2 bv[16];
  // prologue: issue tile 0
#pragma unroll
  for (int q = 0; q < 4; ++q) {
    int c = wid * 4 + q;
    gload16(Abase + (size_t)(c * 8 + arow) * DFF + acol, &As[0][c * 512]);
  }
  {
    const float* bq = Wb + (size_t)(wid * 16) * DM + n2 * 2;
#pragma unroll
    for (int j = 0; j < 16; ++j) bv[j] = *(const float2*)(bq + (size_t)j * DM);
  }

  for (int t = 0; t < 16; ++t) {
    const int cur = t & 1;
    __builtin_amdgcn_s_barrier();
    asm volatile("s_waitcnt vmcnt(0)" ::: "memory");
    bf16x8 q00 = { f2bf(bv[0].x), f2bf(bv[1].x), f2bf(bv[2].x), f2bf(bv[3].x),
                   f2bf(bv[4].x), f2bf(bv[5].x), f2bf(bv[6].x), f2bf(bv[7].x) };
    bf16x8 q01 = { f2bf(bv[8].x), f2bf(bv[9].x), f2bf(bv[10].x), f2bf(bv[11].x),
                   f2bf(bv[12].x), f2bf(bv[13].x), f2bf(bv[14].x), f2bf(bv[15].x) };
    bf16x8 q10 = { f2bf(bv[0].y), f2bf(bv[1].y), f2bf(bv[2].y), f2bf(bv[3].y),
                   f2bf(bv[4].y), f2bf(bv[5].y), f2bf(bv[6].y), f2bf(bv[7].y) };
    bf16x8 q11 = { f2bf(bv[8].y), f2bf(bv[9].y), f2bf(bv[10].y), f2bf(bv[11].y),
                   f2bf(bv[12].y), f2bf(bv[13].y), f2bf(bv[14].y), f2bf(bv[15].y) };
    *(bf16x8*)&Bt[w00] = q00;
    *(bf16x8*)&Bt[w01] = q01;
    *(bf16x8*)&Bt[w10] = q10;
    *(bf16x8*)&Bt[w11] = q11;
    if (t < 15) {
      const int k0 = (t + 1) * 64;
#pragma unroll
      for (int q = 0; q < 4; ++q) {
        int c = wid * 4 + q;
        gload16(Abase + (size_t)(c * 8 + arow) * DFF + k0 + acol, &As[cur ^ 1][c * 512]);
      }
      const float* bq = Wb + (size_t)(k0 + wid * 16) * DM + n2 * 2;
#pragma unroll
      for (int j = 0; j < 16; ++j) bv[j] = *(const float2*)(bq + (size_t)j * DM);
    }
    asm volatile("s_waitcnt lgkmcnt(0)" ::: "memory");
    __builtin_amdgcn_s_barrier();
#pragma unroll
    for (int kh = 0; kh < 2; ++kh) {
      const int kq = kh * 4 + (lane >> 4);
      const int co = (kq ^ (lane & 7)) * 8;
      bf16x8 a[4], b[4];
#pragma unroll
      for (int m = 0; m < 4; ++m)
        a[m] = *(const bf16x8*)&As[cur][(wm * 64 + m * 16 + (lane & 15)) * 64 + co];
#pragma unroll
      for (int n = 0; n < 4; ++n)
        b[n] = *(const bf16x8*)&Bt[(wn * 64 + n * 16 + (lane & 15)) * 64 + co];
#pragma unroll
      for (int m = 0; m < 4; ++m)
#pragma unroll
        for (int n = 0; n < 4; ++n)
          acc[m][n] = __builtin_amdgcn_mfma_f32_16x16x32_bf16(a[m], b[n], acc[m][n], 0, 0, 0);
    }
  }
  float* obase = yd + (size_t)(e * CAP + mt * 128) * DM + nt * 128;
#pragma unroll
  for (int m = 0; m < 4; ++m)
#pragma unroll
    for (int n = 0; n < 4; ++n)
#pragma unroll
      for (int j = 0; j < 4; ++j) {
        int rl = wm * 64 + m * 16 + (lane >> 4) * 4 + j;
        int cl = wn * 64 + n * 16 + (lane & 15);
        obase[(size_t)rl * DM + cl] = acc[m][n][j];
      }
}

// ---------------- combine: out[t] = sum_k w_k * yd[slot_k] ----------------
__global__ __launch_bounds__(256) void k_combine(const int* __restrict__ comb_slot,
                                                 const float* __restrict__ topw,
                                                 const float* __restrict__ yd,
                                                 float* __restrict__ out) {
  int t = blockIdx.x;
  int c = threadIdx.x * 4;
  f32x4 acc = (f32x4)0.f;
#pragma unroll
  for (int j = 0; j < 2; ++j) {
    int s = comb_slot[2 * t + j];
    if (s >= 0) {
      float w = topw[2 * t + j];
      f32x4 v = *(const f32x4*)(yd + (size_t)s * DM + c);
      acc += w * v;
    }
  }
  *(f32x4*)(out + (size_t)t * DM + c) = acc;
}

extern "C" void kernel_launch(void* const* d_in, const int* in_sizes, int n_in,
                              void* d_out, int out_size, void* d_ws, size_t ws_size,
                              hipStream_t stream) {
  const float* hidden = (const float*)d_in[0];
  const int*   idx    = (const int*)d_in[1];
  const float* topw   = (const float*)d_in[2];
  const float* gup    = (const float*)d_in[3];
  const float* down   = (const float*)d_in[4];
  float* out = (float*)d_out;

  char* ws = (char*)d_ws;
  int*   slot_token = (int*)ws;                                   // E*C   = 128KB
  int*   comb_slot  = (int*)(ws + 131072);                        // N     = 64KB
  short* xd  = (short*)(ws + 131072 + 65536);                     // 64MB bf16
  short* act = xd + (size_t)NEXP * CAP * DM;                      // 64MB bf16
  float* yd  = (float*)(act + (size_t)NEXP * CAP * DFF);          // 128MB f32

  k_route<<<NEXP, 256, 0, stream>>>(idx, slot_token, comb_slot);
  k_dispatch<<<NEXP * CAP, 256, 0, stream>>>(hidden, slot_token, xd);
  k_gemm1<<<NEXP * 64, 256, 0, stream>>>(xd, gup, act);
  k_gemm2<<<NEXP * 32, 256, 0, stream>>>(act, down, yd);
  k_combine<<<NTOK, 256, 0, stream>>>(comb_slot, topw, yd, out);
}

// Round 4
// 506.342 us; speedup vs baseline: 1.0313x; 1.0313x over previous
//
#include <hip/hip_runtime.h>
#include <hip/hip_bf16.h>
#include <stdint.h>

#define NTOK   8192
#define DM     1024
#define DFF    1024
#define NEXP   64
#define TOPK   2
#define NEXPAND (NTOK*TOPK)   // 16384
#define CAP    512            // (2*N)/E

typedef __attribute__((ext_vector_type(4))) float f32x4;
typedef __attribute__((ext_vector_type(8))) short bf16x8;
typedef __attribute__((ext_vector_type(4))) short short4v;

__device__ __forceinline__ short f2bf(float f) {
  __hip_bfloat16 h = __float2bfloat16(f);
  union { __hip_bfloat16 h; short s; } u; u.h = h; return u.s;
}
__device__ __forceinline__ float bf2f(short s) {
  union { float f; uint32_t u; } u; u.u = ((uint32_t)(uint16_t)s) << 16; return u.f;
}

__device__ __forceinline__ void gload16(const void* g, void* l) {
  __builtin_amdgcn_global_load_lds(
      (const __attribute__((address_space(1))) unsigned int*)g,
      (__attribute__((address_space(3))) unsigned int*)l, 16, 0, 0);
}

// ---------------- routing: exact sequential per-expert cumcount ----------------
__global__ __launch_bounds__(256) void k_route(const int* __restrict__ idx,
                                               int* __restrict__ slot_token,
                                               int* __restrict__ comb_slot) {
  const int ee = blockIdx.x;
  const int tid = threadIdx.x;
  const int lane = tid & 63;
  const int wv = tid >> 6;
  __shared__ int wsum[4];
  int base = 0;
  for (int it = 0; it < NEXPAND / 256; ++it) {
    int i = it * 256 + tid;
    bool m = (idx[i] == ee);
    unsigned long long bal = __ballot(m);
    int pre = __popcll(bal & ((1ull << lane) - 1ull));
    int wtot = __popcll(bal);
    if (lane == 0) wsum[wv] = wtot;
    __syncthreads();
    int wbase = 0, tot = 0;
#pragma unroll
    for (int w = 0; w < 4; ++w) { if (w < wv) wbase += wsum[w]; tot += wsum[w]; }
    if (m) {
      int pos = base + wbase + pre;
      if (pos < CAP) {
        comb_slot[i] = ee * CAP + pos;
        slot_token[ee * CAP + pos] = i >> 1;   // token index (k=2)
      } else {
        comb_slot[i] = -1;                      // dropped over capacity
      }
    }
    base += tot;
    __syncthreads();
  }
  int filled = base < CAP ? base : CAP;
  for (int p = filled + tid; p < CAP; p += 256) slot_token[ee * CAP + p] = -1;
}

// ---------------- dispatch: gather + f32->bf16 ----------------
__global__ __launch_bounds__(256) void k_dispatch(const float* __restrict__ hidden,
                                                  const int* __restrict__ slot_token,
                                                  short* __restrict__ xd) {
  int row = blockIdx.x;
  int tok = slot_token[row];
  int c = threadIdx.x * 4;
  short4v v;
  if (tok >= 0) {
    float4 f = *(const float4*)(hidden + (size_t)tok * DM + c);
    v[0] = f2bf(f.x); v[1] = f2bf(f.y); v[2] = f2bf(f.z); v[3] = f2bf(f.w);
  } else {
    v[0] = 0; v[1] = 0; v[2] = 0; v[3] = 0;
  }
  *(short4v*)(xd + (size_t)row * DM + c) = v;
}

// LDS tiles: [row][64 bf16] rows of 128B; physical chunk = logical chunk ^ (row&7).
// A tiles DMA'd linear -> pre-swizzle GLOBAL source column. B tiles reg-staged
// with XOR on ds_write/ds_read.
// Pipeline: one __syncthreads per K-step, all buffers double, every load has
// >= one MFMA phase of cover before the barrier drain. No inline asm.

// ---------------- GEMM1: act = silu(x@Wg) * (x@Wu) ----------------
__global__ __launch_bounds__(256) void k_gemm1(const short* __restrict__ xd,
                                               const float* __restrict__ gup,
                                               short* __restrict__ act) {
  __shared__ short As[2][128 * 64];
  __shared__ short Bg[2][64 * 64];
  __shared__ short Bu[2][64 * 64];
  int bid0 = blockIdx.x;
  int bid = (bid0 & 7) * (NEXP * 64 / 8) + (bid0 >> 3);   // XCD chunked swizzle
  const int e  = bid >> 6;
  const int mt = (bid >> 4) & 3;
  const int nt = bid & 15;
  const int tid = threadIdx.x;
  const int lane = tid & 63;
  const int wid = tid >> 6;
  const int wm = wid >> 1;
  const int wn = wid & 1;

  const short* Abase = xd + (size_t)(e * CAP + mt * 128) * DM;
  const float* Wg = gup + (size_t)e * DM * (2 * DFF) + nt * 64;

  const int arow = lane >> 3;
  const int acol = ((lane & 7) ^ arow) * 8;

  const int n2 = tid & 31;
  const int kg = tid >> 5;
  const int r0 = 2 * n2, r1 = 2 * n2 + 1;
  const int w0off = r0 * 64 + ((kg ^ (r0 & 7)) * 8);
  const int w1off = r1 * 64 + ((kg ^ (r1 & 7)) * 8);
  const float* gq0 = Wg + (size_t)(kg * 8) * (2 * DFF) + n2 * 2;

  f32x4 accg[4][2], accu[4][2];
#pragma unroll
  for (int m = 0; m < 4; ++m)
#pragma unroll
    for (int n = 0; n < 2; ++n) { accg[m][n] = (f32x4)0.f; accu[m][n] = (f32x4)0.f; }

  float2 gv[8], uv[8];
  // ---- prologue: stage tile0 (B exposed once), issue A0 DMA + B1 loads ----
#pragma unroll
  for (int j = 0; j < 8; ++j) {
    gv[j] = *(const float2*)(gq0 + (size_t)j * (2 * DFF));
    uv[j] = *(const float2*)(gq0 + (size_t)j * (2 * DFF) + DFF);
  }
  {
    bf16x8 wg0 = { f2bf(gv[0].x), f2bf(gv[1].x), f2bf(gv[2].x), f2bf(gv[3].x),
                   f2bf(gv[4].x), f2bf(gv[5].x), f2bf(gv[6].x), f2bf(gv[7].x) };
    bf16x8 wg1 = { f2bf(gv[0].y), f2bf(gv[1].y), f2bf(gv[2].y), f2bf(gv[3].y),
                   f2bf(gv[4].y), f2bf(gv[5].y), f2bf(gv[6].y), f2bf(gv[7].y) };
    bf16x8 wu0 = { f2bf(uv[0].x), f2bf(uv[1].x), f2bf(uv[2].x), f2bf(uv[3].x),
                   f2bf(uv[4].x), f2bf(uv[5].x), f2bf(uv[6].x), f2bf(uv[7].x) };
    bf16x8 wu1 = { f2bf(uv[0].y), f2bf(uv[1].y), f2bf(uv[2].y), f2bf(uv[3].y),
                   f2bf(uv[4].y), f2bf(uv[5].y), f2bf(uv[6].y), f2bf(uv[7].y) };
    *(bf16x8*)&Bg[0][w0off] = wg0;  *(bf16x8*)&Bg[0][w1off] = wg1;
    *(bf16x8*)&Bu[0][w0off] = wu0;  *(bf16x8*)&Bu[0][w1off] = wu1;
  }
#pragma unroll
  for (int q = 0; q < 4; ++q) {
    int c = wid * 4 + q;
    gload16(Abase + (size_t)(c * 8 + arow) * DM + acol, &As[0][c * 512]);
  }
#pragma unroll
  for (int j = 0; j < 8; ++j) {
    gv[j] = *(const float2*)(gq0 + (size_t)(64 + j * 2 * DFF) * 1 + 0 * DFF + (size_t)64 * (2 * DFF) * 0 + (size_t)j * 0);   // placeholder, replaced below
  }
  // (real B1 issue)
  {
    const float* gq = Wg + (size_t)(64 + kg * 8) * (2 * DFF) + n2 * 2;
#pragma unroll
    for (int j = 0; j < 8; ++j) {
      gv[j] = *(const float2*)(gq + (size_t)j * (2 * DFF));
      uv[j] = *(const float2*)(gq + (size_t)j * (2 * DFF) + DFF);
    }
  }
  __syncthreads();

  for (int t = 0; t < 16; ++t) {
    const int cur = t & 1;
    if (t < 15) {
      // stage B(t+1) from regs (loaded a full K-step ago) into [cur^1]
      bf16x8 wg0 = { f2bf(gv[0].x), f2bf(gv[1].x), f2bf(gv[2].x), f2bf(gv[3].x),
                     f2bf(gv[4].x), f2bf(gv[5].x), f2bf(gv[6].x), f2bf(gv[7].x) };
      bf16x8 wg1 = { f2bf(gv[0].y), f2bf(gv[1].y), f2bf(gv[2].y), f2bf(gv[3].y),
                     f2bf(gv[4].y), f2bf(gv[5].y), f2bf(gv[6].y), f2bf(gv[7].y) };
      bf16x8 wu0 = { f2bf(uv[0].x), f2bf(uv[1].x), f2bf(uv[2].x), f2bf(uv[3].x),
                     f2bf(uv[4].x), f2bf(uv[5].x), f2bf(uv[6].x), f2bf(uv[7].x) };
      bf16x8 wu1 = { f2bf(uv[0].y), f2bf(uv[1].y), f2bf(uv[2].y), f2bf(uv[3].y),
                     f2bf(uv[4].y), f2bf(uv[5].y), f2bf(uv[6].y), f2bf(uv[7].y) };
      *(bf16x8*)&Bg[cur ^ 1][w0off] = wg0;  *(bf16x8*)&Bg[cur ^ 1][w1off] = wg1;
      *(bf16x8*)&Bu[cur ^ 1][w0off] = wu0;  *(bf16x8*)&Bu[cur ^ 1][w1off] = wu1;
      // issue A(t+1) DMA
      const int k0 = (t + 1) * 64;
#pragma unroll
      for (int q = 0; q < 4; ++q) {
        int c = wid * 4 + q;
        gload16(Abase + (size_t)(c * 8 + arow) * DM + k0 + acol, &As[cur ^ 1][c * 512]);
      }
    }
    if (t < 14) {
      // issue B(t+2) reg loads (consumed next iter; cover = MFMA(t)+barrier+MFMA-lead)
      const float* gq = Wg + (size_t)((t + 2) * 64 + kg * 8) * (2 * DFF) + n2 * 2;
#pragma unroll
      for (int j = 0; j < 8; ++j) {
        gv[j] = *(const float2*)(gq + (size_t)j * (2 * DFF));
        uv[j] = *(const float2*)(gq + (size_t)j * (2 * DFF) + DFF);
      }
    }
    // MFMA on tile t
#pragma unroll
    for (int kh = 0; kh < 2; ++kh) {
      const int kq = kh * 4 + (lane >> 4);
      const int co = (kq ^ (lane & 7)) * 8;
      bf16x8 a[4], bgf[2], buf_[2];
#pragma unroll
      for (int m = 0; m < 4; ++m)
        a[m] = *(const bf16x8*)&As[cur][(wm * 64 + m * 16 + (lane & 15)) * 64 + co];
#pragma unroll
      for (int n = 0; n < 2; ++n) {
        bgf[n]  = *(const bf16x8*)&Bg[cur][(wn * 32 + n * 16 + (lane & 15)) * 64 + co];
        buf_[n] = *(const bf16x8*)&Bu[cur][(wn * 32 + n * 16 + (lane & 15)) * 64 + co];
      }
#pragma unroll
      for (int m = 0; m < 4; ++m)
#pragma unroll
        for (int n = 0; n < 2; ++n) {
          accg[m][n] = __builtin_amdgcn_mfma_f32_16x16x32_bf16(a[m], bgf[n], accg[m][n], 0, 0, 0);
          accu[m][n] = __builtin_amdgcn_mfma_f32_16x16x32_bf16(a[m], buf_[n], accu[m][n], 0, 0, 0);
        }
    }
    __syncthreads();
  }
  // fused SwiGLU epilogue -> act bf16
  short* obase = act + (size_t)(e * CAP + mt * 128) * DFF + nt * 64;
#pragma unroll
  for (int m = 0; m < 4; ++m)
#pragma unroll
    for (int n = 0; n < 2; ++n)
#pragma unroll
      for (int j = 0; j < 4; ++j) {
        int rl = wm * 64 + m * 16 + (lane >> 4) * 4 + j;
        int cl = wn * 32 + n * 16 + (lane & 15);
        float g = accg[m][n][j];
        float u = accu[m][n][j];
        float s = (g / (1.f + __expf(-g))) * u;
        obase[(size_t)rl * DFF + cl] = f2bf(s);
      }
}

// ---------------- GEMM2: yd = act @ down (yd stored bf16) ----------------
__global__ __launch_bounds__(256) void k_gemm2(const short* __restrict__ act,
                                               const float* __restrict__ down,
                                               short* __restrict__ yd) {
  __shared__ short As[2][128 * 64];
  __shared__ short Bt[2][128 * 64];
  int bid0 = blockIdx.x;
  int bid = (bid0 & 7) * (NEXP * 32 / 8) + (bid0 >> 3);   // XCD chunked swizzle
  const int e  = bid >> 5;
  const int mt = (bid >> 3) & 3;
  const int nt = bid & 7;
  const int tid = threadIdx.x;
  const int lane = tid & 63;
  const int wid = tid >> 6;
  const int wm = wid >> 1;
  const int wn = wid & 1;

  const short* Abase = act + (size_t)(e * CAP + mt * 128) * DFF;
  const float* Wb = down + (size_t)e * DFF * DM + nt * 128;

  const int arow = lane >> 3;
  const int acol = ((lane & 7) ^ arow) * 8;

  const int n2 = tid & 63;
  const int r0 = 2 * n2, r1 = 2 * n2 + 1;
  const int c0 = wid * 2, c1 = wid * 2 + 1;
  const int w00 = r0 * 64 + ((c0 ^ (r0 & 7)) * 8);
  const int w01 = r0 * 64 + ((c1 ^ (r0 & 7)) * 8);
  const int w10 = r1 * 64 + ((c0 ^ (r1 & 7)) * 8);
  const int w11 = r1 * 64 + ((c1 ^ (r1 & 7)) * 8);

  f32x4 acc[4][4];
#pragma unroll
  for (int m = 0; m < 4; ++m)
#pragma unroll
    for (int n = 0; n < 4; ++n) acc[m][n] = (f32x4)0.f;

  float2 bv[16];
  auto stage_B = [&](int buf) {
    bf16x8 q00 = { f2bf(bv[0].x), f2bf(bv[1].x), f2bf(bv[2].x), f2bf(bv[3].x),
                   f2bf(bv[4].x), f2bf(bv[5].x), f2bf(bv[6].x), f2bf(bv[7].x) };
    bf16x8 q01 = { f2bf(bv[8].x), f2bf(bv[9].x), f2bf(bv[10].x), f2bf(bv[11].x),
                   f2bf(bv[12].x), f2bf(bv[13].x), f2bf(bv[14].x), f2bf(bv[15].x) };
    bf16x8 q10 = { f2bf(bv[0].y), f2bf(bv[1].y), f2bf(bv[2].y), f2bf(bv[3].y),
                   f2bf(bv[4].y), f2bf(bv[5].y), f2bf(bv[6].y), f2bf(bv[7].y) };
    bf16x8 q11 = { f2bf(bv[8].y), f2bf(bv[9].y), f2bf(bv[10].y), f2bf(bv[11].y),
                   f2bf(bv[12].y), f2bf(bv[13].y), f2bf(bv[14].y), f2bf(bv[15].y) };
    *(bf16x8*)&Bt[buf][w00] = q00;  *(bf16x8*)&Bt[buf][w01] = q01;
    *(bf16x8*)&Bt[buf][w10] = q10;  *(bf16x8*)&Bt[buf][w11] = q11;
  };

  // ---- prologue ----
  {
    const float* bq = Wb + (size_t)(wid * 16) * DM + n2 * 2;
#pragma unroll
    for (int j = 0; j < 16; ++j) bv[j] = *(const float2*)(bq + (size_t)j * DM);
  }
  stage_B(0);
#pragma unroll
  for (int q = 0; q < 4; ++q) {
    int c = wid * 4 + q;
    gload16(Abase + (size_t)(c * 8 + arow) * DFF + acol, &As[0][c * 512]);
  }
  {
    const float* bq = Wb + (size_t)(64 + wid * 16) * DM + n2 * 2;
#pragma unroll
    for (int j = 0; j < 16; ++j) bv[j] = *(const float2*)(bq + (size_t)j * DM);
  }
  __syncthreads();

  for (int t = 0; t < 16; ++t) {
    const int cur = t & 1;
    if (t < 15) {
      stage_B(cur ^ 1);
      const int k0 = (t + 1) * 64;
#pragma unroll
      for (int q = 0; q < 4; ++q) {
        int c = wid * 4 + q;
        gload16(Abase + (size_t)(c * 8 + arow) * DFF + k0 + acol, &As[cur ^ 1][c * 512]);
      }
    }
    if (t < 14) {
      const float* bq = Wb + (size_t)((t + 2) * 64 + wid * 16) * DM + n2 * 2;
#pragma unroll
      for (int j = 0; j < 16; ++j) bv[j] = *(const float2*)(bq + (size_t)j * DM);
    }
#pragma unroll
    for (int kh = 0; kh < 2; ++kh) {
      const int kq = kh * 4 + (lane >> 4);
      const int co = (kq ^ (lane & 7)) * 8;
      bf16x8 a[4], b[4];
#pragma unroll
      for (int m = 0; m < 4; ++m)
        a[m] = *(const bf16x8*)&As[cur][(wm * 64 + m * 16 + (lane & 15)) * 64 + co];
#pragma unroll
      for (int n = 0; n < 4; ++n)
        b[n] = *(const bf16x8*)&Bt[cur][(wn * 64 + n * 16 + (lane & 15)) * 64 + co];
#pragma unroll
      for (int m = 0; m < 4; ++m)
#pragma unroll
        for (int n = 0; n < 4; ++n)
          acc[m][n] = __builtin_amdgcn_mfma_f32_16x16x32_bf16(a[m], b[n], acc[m][n], 0, 0, 0);
    }
    __syncthreads();
  }
  short* obase = yd + (size_t)(e * CAP + mt * 128) * DM + nt * 128;
#pragma unroll
  for (int m = 0; m < 4; ++m)
#pragma unroll
    for (int n = 0; n < 4; ++n)
#pragma unroll
      for (int j = 0; j < 4; ++j) {
        int rl = wm * 64 + m * 16 + (lane >> 4) * 4 + j;
        int cl = wn * 64 + n * 16 + (lane & 15);
        obase[(size_t)rl * DM + cl] = f2bf(acc[m][n][j]);
      }
}

// ---------------- combine: out[t] = sum_k w_k * yd[slot_k] ----------------
__global__ __launch_bounds__(256) void k_combine(const int* __restrict__ comb_slot,
                                                 const float* __restrict__ topw,
                                                 const short* __restrict__ yd,
                                                 float* __restrict__ out) {
  int t = blockIdx.x;
  int c = threadIdx.x * 4;
  f32x4 acc = (f32x4)0.f;
#pragma unroll
  for (int j = 0; j < 2; ++j) {
    int s = comb_slot[2 * t + j];
    if (s >= 0) {
      float w = topw[2 * t + j];
      short4v v = *(const short4v*)(yd + (size_t)s * DM + c);
#pragma unroll
      for (int q = 0; q < 4; ++q) acc[q] += w * bf2f(v[q]);
    }
  }
  *(f32x4*)(out + (size_t)t * DM + c) = acc;
}

extern "C" void kernel_launch(void* const* d_in, const int* in_sizes, int n_in,
                              void* d_out, int out_size, void* d_ws, size_t ws_size,
                              hipStream_t stream) {
  const float* hidden = (const float*)d_in[0];
  const int*   idx    = (const int*)d_in[1];
  const float* topw   = (const float*)d_in[2];
  const float* gup    = (const float*)d_in[3];
  const float* down   = (const float*)d_in[4];
  float* out = (float*)d_out;

  char* ws = (char*)d_ws;
  int*   slot_token = (int*)ws;                                   // E*C   = 128KB
  int*   comb_slot  = (int*)(ws + 131072);                        // N     = 64KB
  short* xd  = (short*)(ws + 131072 + 65536);                     // 64MB bf16
  short* act = xd + (size_t)NEXP * CAP * DM;                      // 64MB bf16
  short* yd  = act + (size_t)NEXP * CAP * DFF;                    // 64MB bf16

  k_route<<<NEXP, 256, 0, stream>>>(idx, slot_token, comb_slot);
  k_dispatch<<<NEXP * CAP, 256, 0, stream>>>(hidden, slot_token, xd);
  k_gemm1<<<NEXP * 64, 256, 0, stream>>>(xd, gup, act);
  k_gemm2<<<NEXP * 32, 256, 0, stream>>>(act, down, yd);
  k_combine<<<NTOK, 256, 0, stream>>>(comb_slot, topw, yd, out);
}

// Round 5
// 422.795 us; speedup vs baseline: 1.2351x; 1.1976x over previous
//
#include <hip/hip_runtime.h>
#include <hip/hip_bf16.h>
#include <stdint.h>

#define NTOK   8192
#define DM     1024
#define DFF    1024
#define NEXP   64
#define TOPK   2
#define NEXPAND (NTOK*TOPK)   // 16384
#define CAP    512            // (2*N)/E

typedef __attribute__((ext_vector_type(4))) float f32x4;
typedef __attribute__((ext_vector_type(8))) short bf16x8;
typedef __attribute__((ext_vector_type(4))) short short4v;

__device__ __forceinline__ short f2bf(float f) {
  __hip_bfloat16 h = __float2bfloat16(f);
  union { __hip_bfloat16 h; short s; } u; u.h = h; return u.s;
}
__device__ __forceinline__ float bf2f(short s) {
  union { float f; uint32_t u; } u; u.u = ((uint32_t)(uint16_t)s) << 16; return u.f;
}

__device__ __forceinline__ void gload16(const void* g, void* l) {
  __builtin_amdgcn_global_load_lds(
      (const __attribute__((address_space(1))) unsigned int*)g,
      (__attribute__((address_space(3))) unsigned int*)l, 16, 0, 0);
}

// ---------------- routing: exact sequential per-expert cumcount ----------------
__global__ __launch_bounds__(256) void k_route(const int* __restrict__ idx,
                                               int* __restrict__ slot_token,
                                               int* __restrict__ comb_slot) {
  const int ee = blockIdx.x;
  const int tid = threadIdx.x;
  const int lane = tid & 63;
  const int wv = tid >> 6;
  __shared__ int wsum[4];
  int base = 0;
  for (int it = 0; it < NEXPAND / 256; ++it) {
    int i = it * 256 + tid;
    bool m = (idx[i] == ee);
    unsigned long long bal = __ballot(m);
    int pre = __popcll(bal & ((1ull << lane) - 1ull));
    int wtot = __popcll(bal);
    if (lane == 0) wsum[wv] = wtot;
    __syncthreads();
    int wbase = 0, tot = 0;
#pragma unroll
    for (int w = 0; w < 4; ++w) { if (w < wv) wbase += wsum[w]; tot += wsum[w]; }
    if (m) {
      int pos = base + wbase + pre;
      if (pos < CAP) {
        comb_slot[i] = ee * CAP + pos;
        slot_token[ee * CAP + pos] = i >> 1;   // token index (k=2)
      } else {
        comb_slot[i] = -1;                      // dropped over capacity
      }
    }
    base += tot;
    __syncthreads();
  }
  int filled = base < CAP ? base : CAP;
  for (int p = filled + tid; p < CAP; p += 256) slot_token[ee * CAP + p] = -1;
}

// ---------------- dispatch: gather + f32->bf16 ----------------
__global__ __launch_bounds__(256) void k_dispatch(const float* __restrict__ hidden,
                                                  const int* __restrict__ slot_token,
                                                  short* __restrict__ xd) {
  int row = blockIdx.x;
  int tok = slot_token[row];
  int c = threadIdx.x * 4;
  short4v v;
  if (tok >= 0) {
    float4 f = *(const float4*)(hidden + (size_t)tok * DM + c);
    v[0] = f2bf(f.x); v[1] = f2bf(f.y); v[2] = f2bf(f.z); v[3] = f2bf(f.w);
  } else {
    v[0] = 0; v[1] = 0; v[2] = 0; v[3] = 0;
  }
  *(short4v*)(xd + (size_t)row * DM + c) = v;
}

// LDS tile layout (all tiles [row][32 bf16] = 64B rows, chunks of 8 bf16=16B):
//   physical chunk = logical chunk ^ ((row>>1) & 3)
// A: DMA'd linear (dest = uniform base + lane*16B) -> pre-swizzle GLOBAL source.
// B: reg-staged column-per-thread; XOR applied on ds_write and ds_read.
// Pipeline: BK=32, As/B double-buffered, ONE __syncthreads per K-step; A(t+1)
// DMA + B(t+2) reg loads issued before MFMA(t) (full-phase cover).

// ---------------- GEMM1: act = silu(x@Wg) * (x@Wu) ----------------
// block 256 rows x (64 gate + 64 up), 8 waves, wave tile 64r x (32g+32u)
__global__ __launch_bounds__(512, 4) void k_gemm1(const short* __restrict__ xd,
                                                  const float* __restrict__ gup,
                                                  short* __restrict__ act) {
  __shared__ short As[2][256 * 32];
  __shared__ short Bg[2][64 * 32];
  __shared__ short Bu[2][64 * 32];
  int bid0 = blockIdx.x;
  int bid = (bid0 & 7) * (2048 / 8) + (bid0 >> 3);   // XCD chunked swizzle
  const int e  = bid >> 5;
  const int mt = (bid >> 4) & 1;
  const int nt = bid & 15;
  const int tid = threadIdx.x;
  const int lane = tid & 63;
  const int wid = tid >> 6;
  const int wm = wid >> 1;   // 0..3
  const int wn = wid & 1;    // 0..1

  const short* Abase = xd + (size_t)(e * CAP + mt * 256) * DM;
  const float* Wg = gup + (size_t)e * DM * 2048 + nt * 64;

  // A staging: per issue c in {0,1}: row = c*128 + wid*16 + (lane>>2)
  const int arowloc = wid * 16 + (lane >> 2);
  const int asw = ((lane & 3) ^ ((lane >> 3) & 3)) * 8;   // pre-swizzled src chunk
  // B staging: col-per-thread, 4 k-rows
  const int bn = tid & 63;          // column 0..63
  const int bq = tid >> 6;          // 0..7 -> rows 4bq..4bq+3
  const int boff = bn * 32 + (((bq >> 1) ^ ((bn >> 1) & 3)) * 8) + 4 * (bq & 1);
  // frag read swizzled chunk offset
  const int co = (((lane >> 4) ^ ((lane >> 1) & 3))) * 8;

  f32x4 accg[4][2], accu[4][2];
#pragma unroll
  for (int m = 0; m < 4; ++m)
#pragma unroll
    for (int n = 0; n < 2; ++n) { accg[m][n] = (f32x4)0.f; accu[m][n] = (f32x4)0.f; }

  float gv[4], uv[4];
  // ---- prologue ----
#pragma unroll
  for (int c = 0; c < 2; ++c)
    gload16(Abase + (size_t)(c * 128 + arowloc) * DM + asw, &As[0][c * 4096 + wid * 512]);
  {
    const float* gp = Wg + (size_t)(4 * bq) * 2048 + bn;
#pragma unroll
    for (int j = 0; j < 4; ++j) { gv[j] = gp[(size_t)j * 2048]; uv[j] = gp[(size_t)j * 2048 + 1024]; }
    short4v sg = { f2bf(gv[0]), f2bf(gv[1]), f2bf(gv[2]), f2bf(gv[3]) };
    short4v su = { f2bf(uv[0]), f2bf(uv[1]), f2bf(uv[2]), f2bf(uv[3]) };
    *(short4v*)&Bg[0][boff] = sg;
    *(short4v*)&Bu[0][boff] = su;
  }
#pragma unroll
  for (int c = 0; c < 2; ++c)
    gload16(Abase + (size_t)(c * 128 + arowloc) * DM + 32 + asw, &As[1][c * 4096 + wid * 512]);
  {
    const float* gp = Wg + (size_t)(32 + 4 * bq) * 2048 + bn;
#pragma unroll
    for (int j = 0; j < 4; ++j) { gv[j] = gp[(size_t)j * 2048]; uv[j] = gp[(size_t)j * 2048 + 1024]; }
  }
  __syncthreads();

  for (int t = 0; t < 32; ++t) {
    const int cur = t & 1;
    if (t < 31) {
      // stage B(t+1) from regs into the buffer freed at the last barrier
      short4v sg = { f2bf(gv[0]), f2bf(gv[1]), f2bf(gv[2]), f2bf(gv[3]) };
      short4v su = { f2bf(uv[0]), f2bf(uv[1]), f2bf(uv[2]), f2bf(uv[3]) };
      *(short4v*)&Bg[cur ^ 1][boff] = sg;
      *(short4v*)&Bu[cur ^ 1][boff] = su;
    }
    if (t >= 1 && t < 31) {
      const int k0 = (t + 1) * 32;
#pragma unroll
      for (int c = 0; c < 2; ++c)
        gload16(Abase + (size_t)(c * 128 + arowloc) * DM + k0 + asw, &As[cur ^ 1][c * 4096 + wid * 512]);
    }
    if (t < 30) {
      const float* gp = Wg + (size_t)((t + 2) * 32 + 4 * bq) * 2048 + bn;
#pragma unroll
      for (int j = 0; j < 4; ++j) { gv[j] = gp[(size_t)j * 2048]; uv[j] = gp[(size_t)j * 2048 + 1024]; }
    }
    // MFMA on tile t
    bf16x8 a[4], bgf[2], buf_[2];
#pragma unroll
    for (int m = 0; m < 4; ++m)
      a[m] = *(const bf16x8*)&As[cur][(wm * 64 + m * 16 + (lane & 15)) * 32 + co];
#pragma unroll
    for (int n = 0; n < 2; ++n) {
      bgf[n]  = *(const bf16x8*)&Bg[cur][(wn * 32 + n * 16 + (lane & 15)) * 32 + co];
      buf_[n] = *(const bf16x8*)&Bu[cur][(wn * 32 + n * 16 + (lane & 15)) * 32 + co];
    }
#pragma unroll
    for (int m = 0; m < 4; ++m)
#pragma unroll
      for (int n = 0; n < 2; ++n) {
        accg[m][n] = __builtin_amdgcn_mfma_f32_16x16x32_bf16(a[m], bgf[n], accg[m][n], 0, 0, 0);
        accu[m][n] = __builtin_amdgcn_mfma_f32_16x16x32_bf16(a[m], buf_[n], accu[m][n], 0, 0, 0);
      }
    __syncthreads();
  }
  // fused SwiGLU epilogue -> act bf16
  short* obase = act + (size_t)(e * CAP + mt * 256) * DFF + nt * 64;
#pragma unroll
  for (int m = 0; m < 4; ++m)
#pragma unroll
    for (int n = 0; n < 2; ++n)
#pragma unroll
      for (int j = 0; j < 4; ++j) {
        int rl = wm * 64 + m * 16 + (lane >> 4) * 4 + j;
        int cl = wn * 32 + n * 16 + (lane & 15);
        float g = accg[m][n][j];
        float u = accu[m][n][j];
        float s = (g / (1.f + __expf(-g))) * u;
        obase[(size_t)rl * DFF + cl] = f2bf(s);
      }
}

// ---------------- GEMM2: yd = act @ down (yd bf16) ----------------
// block 256 rows x 128 cols, 8 waves, wave tile 64x64
__global__ __launch_bounds__(512, 4) void k_gemm2(const short* __restrict__ act,
                                                  const float* __restrict__ down,
                                                  short* __restrict__ yd) {
  __shared__ short As[2][256 * 32];
  __shared__ short Bt[2][128 * 32];
  int bid0 = blockIdx.x;
  int bid = (bid0 & 7) * (1024 / 8) + (bid0 >> 3);   // XCD chunked swizzle
  const int e  = bid >> 4;
  const int mt = (bid >> 3) & 1;
  const int nt = bid & 7;
  const int tid = threadIdx.x;
  const int lane = tid & 63;
  const int wid = tid >> 6;
  const int wm = wid >> 1;   // 0..3
  const int wn = wid & 1;    // 0..1

  const short* Abase = act + (size_t)(e * CAP + mt * 256) * DFF;
  const float* Wb = down + (size_t)e * DFF * DM + nt * 128;

  const int arowloc = wid * 16 + (lane >> 2);
  const int asw = ((lane & 3) ^ ((lane >> 3) & 3)) * 8;
  // B staging: col-per-thread, 8 k-rows (one full chunk)
  const int bn = tid & 127;         // column 0..127
  const int bq = tid >> 7;          // 0..3 -> rows 8bq..8bq+7
  const int boff = bn * 32 + ((bq ^ ((bn >> 1) & 3)) * 8);
  const int co = (((lane >> 4) ^ ((lane >> 1) & 3))) * 8;

  f32x4 acc[4][4];
#pragma unroll
  for (int m = 0; m < 4; ++m)
#pragma unroll
    for (int n = 0; n < 4; ++n) acc[m][n] = (f32x4)0.f;

  float bv[8];
  // ---- prologue ----
#pragma unroll
  for (int c = 0; c < 2; ++c)
    gload16(Abase + (size_t)(c * 128 + arowloc) * DFF + asw, &As[0][c * 4096 + wid * 512]);
  {
    const float* bp = Wb + (size_t)(8 * bq) * DM + bn;
#pragma unroll
    for (int j = 0; j < 8; ++j) bv[j] = bp[(size_t)j * DM];
    bf16x8 sb = { f2bf(bv[0]), f2bf(bv[1]), f2bf(bv[2]), f2bf(bv[3]),
                  f2bf(bv[4]), f2bf(bv[5]), f2bf(bv[6]), f2bf(bv[7]) };
    *(bf16x8*)&Bt[0][boff] = sb;
  }
#pragma unroll
  for (int c = 0; c < 2; ++c)
    gload16(Abase + (size_t)(c * 128 + arowloc) * DFF + 32 + asw, &As[1][c * 4096 + wid * 512]);
  {
    const float* bp = Wb + (size_t)(32 + 8 * bq) * DM + bn;
#pragma unroll
    for (int j = 0; j < 8; ++j) bv[j] = bp[(size_t)j * DM];
  }
  __syncthreads();

  for (int t = 0; t < 32; ++t) {
    const int cur = t & 1;
    if (t < 31) {
      bf16x8 sb = { f2bf(bv[0]), f2bf(bv[1]), f2bf(bv[2]), f2bf(bv[3]),
                    f2bf(bv[4]), f2bf(bv[5]), f2bf(bv[6]), f2bf(bv[7]) };
      *(bf16x8*)&Bt[cur ^ 1][boff] = sb;
    }
    if (t >= 1 && t < 31) {
      const int k0 = (t + 1) * 32;
#pragma unroll
      for (int c = 0; c < 2; ++c)
        gload16(Abase + (size_t)(c * 128 + arowloc) * DFF + k0 + asw, &As[cur ^ 1][c * 4096 + wid * 512]);
    }
    if (t < 30) {
      const float* bp = Wb + (size_t)((t + 2) * 32 + 8 * bq) * DM + bn;
#pragma unroll
      for (int j = 0; j < 8; ++j) bv[j] = bp[(size_t)j * DM];
    }
    bf16x8 a[4], b[4];
#pragma unroll
    for (int m = 0; m < 4; ++m)
      a[m] = *(const bf16x8*)&As[cur][(wm * 64 + m * 16 + (lane & 15)) * 32 + co];
#pragma unroll
    for (int n = 0; n < 4; ++n)
      b[n] = *(const bf16x8*)&Bt[cur][(wn * 64 + n * 16 + (lane & 15)) * 32 + co];
#pragma unroll
    for (int m = 0; m < 4; ++m)
#pragma unroll
      for (int n = 0; n < 4; ++n)
        acc[m][n] = __builtin_amdgcn_mfma_f32_16x16x32_bf16(a[m], b[n], acc[m][n], 0, 0, 0);
    __syncthreads();
  }
  short* obase = yd + (size_t)(e * CAP + mt * 256) * DM + nt * 128;
#pragma unroll
  for (int m = 0; m < 4; ++m)
#pragma unroll
    for (int n = 0; n < 4; ++n)
#pragma unroll
      for (int j = 0; j < 4; ++j) {
        int rl = wm * 64 + m * 16 + (lane >> 4) * 4 + j;
        int cl = wn * 64 + n * 16 + (lane & 15);
        obase[(size_t)rl * DM + cl] = f2bf(acc[m][n][j]);
      }
}

// ---------------- combine: out[t] = sum_k w_k * yd[slot_k] ----------------
__global__ __launch_bounds__(256) void k_combine(const int* __restrict__ comb_slot,
                                                 const float* __restrict__ topw,
                                                 const short* __restrict__ yd,
                                                 float* __restrict__ out) {
  int t = blockIdx.x;
  int c = threadIdx.x * 4;
  f32x4 acc = (f32x4)0.f;
#pragma unroll
  for (int j = 0; j < 2; ++j) {
    int s = comb_slot[2 * t + j];
    if (s >= 0) {
      float w = topw[2 * t + j];
      short4v v = *(const short4v*)(yd + (size_t)s * DM + c);
#pragma unroll
      for (int q = 0; q < 4; ++q) acc[q] += w * bf2f(v[q]);
    }
  }
  *(f32x4*)(out + (size_t)t * DM + c) = acc;
}

extern "C" void kernel_launch(void* const* d_in, const int* in_sizes, int n_in,
                              void* d_out, int out_size, void* d_ws, size_t ws_size,
                              hipStream_t stream) {
  const float* hidden = (const float*)d_in[0];
  const int*   idx    = (const int*)d_in[1];
  const float* topw   = (const float*)d_in[2];
  const float* gup    = (const float*)d_in[3];
  const float* down   = (const float*)d_in[4];
  float* out = (float*)d_out;

  char* ws = (char*)d_ws;
  int*   slot_token = (int*)ws;                                   // E*C   = 128KB
  int*   comb_slot  = (int*)(ws + 131072);                        // N     = 64KB
  short* xd  = (short*)(ws + 131072 + 65536);                     // 64MB bf16
  short* act = xd + (size_t)NEXP * CAP * DM;                      // 64MB bf16
  short* yd  = act + (size_t)NEXP * CAP * DFF;                    // 64MB bf16

  k_route<<<NEXP, 256, 0, stream>>>(idx, slot_token, comb_slot);
  k_dispatch<<<NEXP * CAP, 256, 0, stream>>>(hidden, slot_token, xd);
  k_gemm1<<<2048, 512, 0, stream>>>(xd, gup, act);
  k_gemm2<<<1024, 512, 0, stream>>>(act, down, yd);
  k_combine<<<NTOK, 256, 0, stream>>>(comb_slot, topw, yd, out);
}

// Round 6
// 396.578 us; speedup vs baseline: 1.3168x; 1.0661x over previous
//
#include <hip/hip_runtime.h>
#include <hip/hip_bf16.h>
#include <stdint.h>

#define NTOK   8192
#define DM     1024
#define DFF    1024
#define NEXP   64
#define TOPK   2
#define NEXPAND (NTOK*TOPK)   // 16384
#define CAP    512            // (2*N)/E

#define UNROLL _Pragma("unroll")

typedef __attribute__((ext_vector_type(4))) float f32x4;
typedef __attribute__((ext_vector_type(8))) short bf16x8;
typedef __attribute__((ext_vector_type(4))) short short4v;

__device__ __forceinline__ short f2bf(float f) {
  __hip_bfloat16 h = __float2bfloat16(f);
  union { __hip_bfloat16 h; short s; } u; u.h = h; return u.s;
}
__device__ __forceinline__ float bf2f(short s) {
  union { float f; uint32_t u; } u; u.u = ((uint32_t)(uint16_t)s) << 16; return u.f;
}

__device__ __forceinline__ void gload16(const void* g, void* l) {
  __builtin_amdgcn_global_load_lds(
      (const __attribute__((address_space(1))) unsigned int*)g,
      (__attribute__((address_space(3))) unsigned int*)l, 16, 0, 0);
}

// ---------------- routing: exact sequential per-expert cumcount ----------------
__global__ __launch_bounds__(256) void k_route(const int* __restrict__ idx,
                                               int* __restrict__ slot_token,
                                               int* __restrict__ comb_slot) {
  const int ee = blockIdx.x;
  const int tid = threadIdx.x;
  const int lane = tid & 63;
  const int wv = tid >> 6;
  __shared__ int wsum[4];
  int base = 0;
  for (int it = 0; it < NEXPAND / 256; ++it) {
    int i = it * 256 + tid;
    bool m = (idx[i] == ee);
    unsigned long long bal = __ballot(m);
    int pre = __popcll(bal & ((1ull << lane) - 1ull));
    int wtot = __popcll(bal);
    if (lane == 0) wsum[wv] = wtot;
    __syncthreads();
    int wbase = 0, tot = 0;
UNROLL
    for (int w = 0; w < 4; ++w) { if (w < wv) wbase += wsum[w]; tot += wsum[w]; }
    if (m) {
      int pos = base + wbase + pre;
      if (pos < CAP) {
        comb_slot[i] = ee * CAP + pos;
        slot_token[ee * CAP + pos] = i >> 1;   // token index (k=2)
      } else {
        comb_slot[i] = -1;                      // dropped over capacity
      }
    }
    base += tot;
    __syncthreads();
  }
  int filled = base < CAP ? base : CAP;
  for (int p = filled + tid; p < CAP; p += 256) slot_token[ee * CAP + p] = -1;
}

// ---------------- dispatch: gather + f32->bf16 ----------------
__global__ __launch_bounds__(256) void k_dispatch(const float* __restrict__ hidden,
                                                  const int* __restrict__ slot_token,
                                                  short* __restrict__ xd) {
  int row = blockIdx.x;
  int tok = slot_token[row];
  int c = threadIdx.x * 4;
  short4v v;
  if (tok >= 0) {
    float4 f = *(const float4*)(hidden + (size_t)tok * DM + c);
    v[0] = f2bf(f.x); v[1] = f2bf(f.y); v[2] = f2bf(f.z); v[3] = f2bf(f.w);
  } else {
    v[0] = 0; v[1] = 0; v[2] = 0; v[3] = 0;
  }
  *(short4v*)(xd + (size_t)row * DM + c) = v;
}

// LDS layout: tiles [row][32 bf16] (64B rows, 16B chunks);
//   physical chunk = logical chunk ^ ((row>>1) & 3).
// A DMA'd linear -> pre-swizzled GLOBAL source; B reg-staged with XOR write/read.
// K-loop protocol (T3/T4): ONE raw s_barrier per K-step; counted vmcnt(8)
// drains only the A-DMA (B weight loads stay in flight a full K-step);
// lgkmcnt(0) covers ds_writes. No vmcnt(0) in the main loop.

// ---------------- GEMM1: act = silu(x@Wg) * (x@Wu) ----------------
// block 256 rows x (64 gate + 64 up), 8 waves, wave tile 64r x (32g+32u)
__global__ __launch_bounds__(512, 4) void k_gemm1(const short* __restrict__ xd,
                                                  const float* __restrict__ gup,
                                                  short* __restrict__ act) {
  __shared__ short As[2][256 * 32];
  __shared__ short Bg[2][64 * 32];
  __shared__ short Bu[2][64 * 32];
  int bid0 = blockIdx.x;
  int bid = (bid0 & 7) * (2048 / 8) + (bid0 >> 3);   // XCD chunked swizzle
  const int e  = bid >> 5;
  const int mt = (bid >> 4) & 1;
  const int nt = bid & 15;
  const int tid = threadIdx.x;
  const int lane = tid & 63;
  const int wid = tid >> 6;
  const int wm = wid >> 1;   // 0..3
  const int wn = wid & 1;    // 0..1

  const short* Abase = xd + (size_t)(e * CAP + mt * 256) * DM;
  const float* Wg = gup + (size_t)e * DM * 2048 + nt * 64;

  const int arowloc = wid * 16 + (lane >> 2);
  const int asw = ((lane & 3) ^ ((lane >> 3) & 3)) * 8;   // pre-swizzled src chunk
  const int bn = tid & 63;          // column 0..63
  const int bq = tid >> 6;          // 0..7 -> rows 4bq..4bq+3
  const int boff = bn * 32 + (((bq >> 1) ^ ((bn >> 1) & 3)) * 8) + 4 * (bq & 1);
  const int co = (((lane >> 4) ^ ((lane >> 1) & 3))) * 8;

  f32x4 accg[4][2], accu[4][2];
UNROLL
  for (int m = 0; m < 4; ++m)
UNROLL
    for (int n = 0; n < 2; ++n) { accg[m][n] = (f32x4)0.f; accu[m][n] = (f32x4)0.f; }

  float gvA[4], uvA[4], gvB[4], uvB[4];

  // ---- prologue: A(0) DMA; B(0)->bvA; B(1)->bvB; stage B(0); barrier ----
  gload16(Abase + (size_t)(arowloc) * DM + asw, &As[0][wid * 512]);
  gload16(Abase + (size_t)(128 + arowloc) * DM + asw, &As[0][4096 + wid * 512]);
  {
    const float* gp = Wg + (size_t)(4 * bq) * 2048 + bn;
UNROLL
    for (int j = 0; j < 4; ++j) { gvA[j] = gp[(size_t)j * 2048]; uvA[j] = gp[(size_t)j * 2048 + 1024]; }
  }
  {
    const float* gp = Wg + (size_t)(32 + 4 * bq) * 2048 + bn;
UNROLL
    for (int j = 0; j < 4; ++j) { gvB[j] = gp[(size_t)j * 2048]; uvB[j] = gp[(size_t)j * 2048 + 1024]; }
  }
  {
    // auto-wait here drains A(0) (older) + bvA; bvB stays in flight
    short4v sg = { f2bf(gvA[0]), f2bf(gvA[1]), f2bf(gvA[2]), f2bf(gvA[3]) };
    short4v su = { f2bf(uvA[0]), f2bf(uvA[1]), f2bf(uvA[2]), f2bf(uvA[3]) };
    *(short4v*)&Bg[0][boff] = sg;
    *(short4v*)&Bu[0][boff] = su;
  }
  asm volatile("s_waitcnt lgkmcnt(0)" ::: "memory");
  __builtin_amdgcn_s_barrier();
  __builtin_amdgcn_sched_barrier(0);

#define G1_BODY(T, CUR, GR, UR, GF, UF) do {                                   \
    const int t_ = (T);                                                        \
    if (t_ < 31) {                                                             \
      const int k0_ = (t_ + 1) * 32;                                           \
      gload16(Abase + (size_t)(arowloc) * DM + k0_ + asw,                      \
              &As[(CUR) ^ 1][wid * 512]);                                      \
      gload16(Abase + (size_t)(128 + arowloc) * DM + k0_ + asw,                \
              &As[(CUR) ^ 1][4096 + wid * 512]);                               \
    }                                                                          \
    if (t_ < 30) {                                                             \
      const float* gp_ = Wg + (size_t)((t_ + 2) * 32 + 4 * bq) * 2048 + bn;    \
      GF[0] = gp_[0];    GF[1] = gp_[2048]; GF[2] = gp_[4096]; GF[3] = gp_[6144]; \
      UF[0] = gp_[1024]; UF[1] = gp_[3072]; UF[2] = gp_[5120]; UF[3] = gp_[7168]; \
    }                                                                          \
    if (t_ < 31) {                                                             \
      short4v sg_ = { f2bf(GR[0]), f2bf(GR[1]), f2bf(GR[2]), f2bf(GR[3]) };    \
      short4v su_ = { f2bf(UR[0]), f2bf(UR[1]), f2bf(UR[2]), f2bf(UR[3]) };    \
      *(short4v*)&Bg[(CUR) ^ 1][boff] = sg_;                                   \
      *(short4v*)&Bu[(CUR) ^ 1][boff] = su_;                                   \
    }                                                                          \
    {                                                                          \
      bf16x8 a_[4], bg_[2], bu_[2];                                            \
UNROLL                                                                         \
      for (int m = 0; m < 4; ++m)                                              \
        a_[m] = *(const bf16x8*)&As[CUR][(wm * 64 + m * 16 + (lane & 15)) * 32 + co]; \
UNROLL                                                                         \
      for (int n = 0; n < 2; ++n) {                                            \
        bg_[n] = *(const bf16x8*)&Bg[CUR][(wn * 32 + n * 16 + (lane & 15)) * 32 + co]; \
        bu_[n] = *(const bf16x8*)&Bu[CUR][(wn * 32 + n * 16 + (lane & 15)) * 32 + co]; \
      }                                                                        \
UNROLL                                                                         \
      for (int m = 0; m < 4; ++m)                                              \
UNROLL                                                                         \
        for (int n = 0; n < 2; ++n) {                                          \
          accg[m][n] = __builtin_amdgcn_mfma_f32_16x16x32_bf16(a_[m], bg_[n], accg[m][n], 0, 0, 0); \
          accu[m][n] = __builtin_amdgcn_mfma_f32_16x16x32_bf16(a_[m], bu_[n], accu[m][n], 0, 0, 0); \
        }                                                                      \
    }                                                                          \
    asm volatile("s_waitcnt vmcnt(8)" ::: "memory");                           \
    asm volatile("s_waitcnt lgkmcnt(0)" ::: "memory");                         \
    __builtin_amdgcn_s_barrier();                                              \
    __builtin_amdgcn_sched_barrier(0);                                         \
  } while (0)

  for (int t2 = 0; t2 < 32; t2 += 2) {
    G1_BODY(t2,     0, gvB, uvB, gvA, uvA);
    G1_BODY(t2 + 1, 1, gvA, uvA, gvB, uvB);
  }
#undef G1_BODY

  // fused SwiGLU epilogue -> act bf16
  short* obase = act + (size_t)(e * CAP + mt * 256) * DFF + nt * 64;
UNROLL
  for (int m = 0; m < 4; ++m)
UNROLL
    for (int n = 0; n < 2; ++n)
UNROLL
      for (int j = 0; j < 4; ++j) {
        int rl = wm * 64 + m * 16 + (lane >> 4) * 4 + j;
        int cl = wn * 32 + n * 16 + (lane & 15);
        float g = accg[m][n][j];
        float u = accu[m][n][j];
        float s = (g / (1.f + __expf(-g))) * u;
        obase[(size_t)rl * DFF + cl] = f2bf(s);
      }
}

// ---------------- GEMM2: yd = act @ down (yd bf16) ----------------
// block 256 rows x 128 cols, 8 waves, wave tile 64x64
__global__ __launch_bounds__(512, 4) void k_gemm2(const short* __restrict__ act,
                                                  const float* __restrict__ down,
                                                  short* __restrict__ yd) {
  __shared__ short As[2][256 * 32];
  __shared__ short Bt[2][128 * 32];
  int bid0 = blockIdx.x;
  int bid = (bid0 & 7) * (1024 / 8) + (bid0 >> 3);   // XCD chunked swizzle
  const int e  = bid >> 4;
  const int mt = (bid >> 3) & 1;
  const int nt = bid & 7;
  const int tid = threadIdx.x;
  const int lane = tid & 63;
  const int wid = tid >> 6;
  const int wm = wid >> 1;   // 0..3
  const int wn = wid & 1;    // 0..1

  const short* Abase = act + (size_t)(e * CAP + mt * 256) * DFF;
  const float* Wb = down + (size_t)e * DFF * DM + nt * 128;

  const int arowloc = wid * 16 + (lane >> 2);
  const int asw = ((lane & 3) ^ ((lane >> 3) & 3)) * 8;
  const int bn = tid & 127;         // column 0..127
  const int bq = tid >> 7;          // 0..3 -> rows 8bq..8bq+7
  const int boff = bn * 32 + ((bq ^ ((bn >> 1) & 3)) * 8);
  const int co = (((lane >> 4) ^ ((lane >> 1) & 3))) * 8;

  f32x4 acc[4][4];
UNROLL
  for (int m = 0; m < 4; ++m)
UNROLL
    for (int n = 0; n < 4; ++n) acc[m][n] = (f32x4)0.f;

  float bvA[8], bvB[8];

  // ---- prologue ----
  gload16(Abase + (size_t)(arowloc) * DFF + asw, &As[0][wid * 512]);
  gload16(Abase + (size_t)(128 + arowloc) * DFF + asw, &As[0][4096 + wid * 512]);
  {
    const float* bp = Wb + (size_t)(8 * bq) * DM + bn;
UNROLL
    for (int j = 0; j < 8; ++j) bvA[j] = bp[(size_t)j * DM];
  }
  {
    const float* bp = Wb + (size_t)(32 + 8 * bq) * DM + bn;
UNROLL
    for (int j = 0; j < 8; ++j) bvB[j] = bp[(size_t)j * DM];
  }
  {
    bf16x8 sb = { f2bf(bvA[0]), f2bf(bvA[1]), f2bf(bvA[2]), f2bf(bvA[3]),
                  f2bf(bvA[4]), f2bf(bvA[5]), f2bf(bvA[6]), f2bf(bvA[7]) };
    *(bf16x8*)&Bt[0][boff] = sb;
  }
  asm volatile("s_waitcnt lgkmcnt(0)" ::: "memory");
  __builtin_amdgcn_s_barrier();
  __builtin_amdgcn_sched_barrier(0);

#define G2_BODY(T, CUR, BR, BF) do {                                           \
    const int t_ = (T);                                                        \
    if (t_ < 31) {                                                             \
      const int k0_ = (t_ + 1) * 32;                                           \
      gload16(Abase + (size_t)(arowloc) * DFF + k0_ + asw,                     \
              &As[(CUR) ^ 1][wid * 512]);                                      \
      gload16(Abase + (size_t)(128 + arowloc) * DFF + k0_ + asw,               \
              &As[(CUR) ^ 1][4096 + wid * 512]);                               \
    }                                                                          \
    if (t_ < 30) {                                                             \
      const float* bp_ = Wb + (size_t)((t_ + 2) * 32 + 8 * bq) * DM + bn;      \
      BF[0] = bp_[0];        BF[1] = bp_[DM];     BF[2] = bp_[2 * DM];         \
      BF[3] = bp_[3 * DM];   BF[4] = bp_[4 * DM]; BF[5] = bp_[5 * DM];         \
      BF[6] = bp_[6 * DM];   BF[7] = bp_[7 * DM];                              \
    }                                                                          \
    if (t_ < 31) {                                                             \
      bf16x8 sb_ = { f2bf(BR[0]), f2bf(BR[1]), f2bf(BR[2]), f2bf(BR[3]),       \
                     f2bf(BR[4]), f2bf(BR[5]), f2bf(BR[6]), f2bf(BR[7]) };     \
      *(bf16x8*)&Bt[(CUR) ^ 1][boff] = sb_;                                    \
    }                                                                          \
    {                                                                          \
      bf16x8 a_[4], b_[4];                                                     \
UNROLL                                                                         \
      for (int m = 0; m < 4; ++m)                                              \
        a_[m] = *(const bf16x8*)&As[CUR][(wm * 64 + m * 16 + (lane & 15)) * 32 + co]; \
UNROLL                                                                         \
      for (int n = 0; n < 4; ++n)                                              \
        b_[n] = *(const bf16x8*)&Bt[CUR][(wn * 64 + n * 16 + (lane & 15)) * 32 + co]; \
UNROLL                                                                         \
      for (int m = 0; m < 4; ++m)                                              \
UNROLL                                                                         \
        for (int n = 0; n < 4; ++n)                                            \
          acc[m][n] = __builtin_amdgcn_mfma_f32_16x16x32_bf16(a_[m], b_[n], acc[m][n], 0, 0, 0); \
    }                                                                          \
    asm volatile("s_waitcnt vmcnt(8)" ::: "memory");                           \
    asm volatile("s_waitcnt lgkmcnt(0)" ::: "memory");                         \
    __builtin_amdgcn_s_barrier();                                              \
    __builtin_amdgcn_sched_barrier(0);                                         \
  } while (0)

  for (int t2 = 0; t2 < 32; t2 += 2) {
    G2_BODY(t2,     0, bvB, bvA);
    G2_BODY(t2 + 1, 1, bvA, bvB);
  }
#undef G2_BODY

  short* obase = yd + (size_t)(e * CAP + mt * 256) * DM + nt * 128;
UNROLL
  for (int m = 0; m < 4; ++m)
UNROLL
    for (int n = 0; n < 4; ++n)
UNROLL
      for (int j = 0; j < 4; ++j) {
        int rl = wm * 64 + m * 16 + (lane >> 4) * 4 + j;
        int cl = wn * 64 + n * 16 + (lane & 15);
        obase[(size_t)rl * DM + cl] = f2bf(acc[m][n][j]);
      }
}

// ---------------- combine: out[t] = sum_k w_k * yd[slot_k] ----------------
__global__ __launch_bounds__(256) void k_combine(const int* __restrict__ comb_slot,
                                                 const float* __restrict__ topw,
                                                 const short* __restrict__ yd,
                                                 float* __restrict__ out) {
  int t = blockIdx.x;
  int c = threadIdx.x * 4;
  f32x4 acc = (f32x4)0.f;
UNROLL
  for (int j = 0; j < 2; ++j) {
    int s = comb_slot[2 * t + j];
    if (s >= 0) {
      float w = topw[2 * t + j];
      short4v v = *(const short4v*)(yd + (size_t)s * DM + c);
UNROLL
      for (int q = 0; q < 4; ++q) acc[q] += w * bf2f(v[q]);
    }
  }
  *(f32x4*)(out + (size_t)t * DM + c) = acc;
}

extern "C" void kernel_launch(void* const* d_in, const int* in_sizes, int n_in,
                              void* d_out, int out_size, void* d_ws, size_t ws_size,
                              hipStream_t stream) {
  const float* hidden = (const float*)d_in[0];
  const int*   idx    = (const int*)d_in[1];
  const float* topw   = (const float*)d_in[2];
  const float* gup    = (const float*)d_in[3];
  const float* down   = (const float*)d_in[4];
  float* out = (float*)d_out;

  char* ws = (char*)d_ws;
  int*   slot_token = (int*)ws;                                   // E*C   = 128KB
  int*   comb_slot  = (int*)(ws + 131072);                        // N     = 64KB
  short* xd  = (short*)(ws + 131072 + 65536);                     // 64MB bf16
  short* act = xd + (size_t)NEXP * CAP * DM;                      // 64MB bf16
  short* yd  = act + (size_t)NEXP * CAP * DFF;                    // 64MB bf16

  k_route<<<NEXP, 256, 0, stream>>>(idx, slot_token, comb_slot);
  k_dispatch<<<NEXP * CAP, 256, 0, stream>>>(hidden, slot_token, xd);
  k_gemm1<<<2048, 512, 0, stream>>>(xd, gup, act);
  k_gemm2<<<1024, 512, 0, stream>>>(act, down, yd);
  k_combine<<<NTOK, 256, 0, stream>>>(comb_slot, topw, yd, out);
}